// Round 6
// baseline (923.180 us; speedup 1.0000x reference)
//
#include <hip/hip_runtime.h>

// ---------------- degree / norm ----------------

__global__ __launch_bounds__(256) void hist_kernel(const int* __restrict__ dst,
                                                   int* __restrict__ hist, int E) {
    int e = blockIdx.x * 256 + threadIdx.x;
    if (e < E) atomicAdd(&hist[dst[e]], 1);
}

__global__ __launch_bounds__(256) void dis_kernel(const int* __restrict__ hist,
                                                  float* __restrict__ dis, int N) {
    int n = blockIdx.x * 256 + threadIdx.x;
    if (n < N) dis[n] = 1.0f / sqrtf((float)(hist[n] + 1));  // +1 self-loop; deg>=1
}

// ---------------- CSR build: reduce -> top scan -> final scan -> fill ----------------

__global__ __launch_bounds__(256) void scan_part_kernel(const int* __restrict__ hist,
                                                        int* __restrict__ partials, int n) {
    __shared__ int sdata[256];
    int i = blockIdx.x * 256 + threadIdx.x;
    int t = threadIdx.x;
    sdata[t] = (i < n) ? hist[i] : 0;
    __syncthreads();
    for (int off = 128; off > 0; off >>= 1) {
        if (t < off) sdata[t] += sdata[t + off];
        __syncthreads();
    }
    if (t == 0) partials[blockIdx.x] = sdata[0];
}

__global__ __launch_bounds__(1024) void scan_top_kernel(int* __restrict__ partials, int nb) {
    __shared__ int sdata[1024];
    int t = threadIdx.x;
    int v = (t < nb) ? partials[t] : 0;
    sdata[t] = v;
    __syncthreads();
    for (int off = 1; off < 1024; off <<= 1) {
        int x = (t >= off) ? sdata[t - off] : 0;
        __syncthreads();
        sdata[t] += x;
        __syncthreads();
    }
    if (t < nb) partials[t] = sdata[t] - v;  // exclusive
}

__global__ __launch_bounds__(256) void scan_final_kernel(const int* __restrict__ hist,
                                                         const int* __restrict__ partials,
                                                         int* __restrict__ row_ptr, int n) {
    __shared__ int sdata[256];
    int i = blockIdx.x * 256 + threadIdx.x;
    int t = threadIdx.x;
    int v = (i < n) ? hist[i] : 0;
    sdata[t] = v;
    __syncthreads();
    for (int off = 1; off < 256; off <<= 1) {
        int x = (t >= off) ? sdata[t - off] : 0;
        __syncthreads();
        sdata[t] += x;
        __syncthreads();
    }
    int base = partials[blockIdx.x];
    if (i < n) row_ptr[i] = base + sdata[t] - v;  // exclusive
    if (i == n - 1) row_ptr[n] = base + sdata[t]; // total = E
}

// dst-range pass: only edges with dst in [lo,hi) are scattered this pass, so the
// active write window of src_sorted is ~1.6 MB -> L2-resident -> dense writeback.
__global__ __launch_bounds__(256) void fill_kernel(const int* __restrict__ src,
                                                   const int* __restrict__ dst,
                                                   const int* __restrict__ row_ptr,
                                                   int* __restrict__ cursor,
                                                   int* __restrict__ src_sorted, int E,
                                                   int lo, int hi) {
    int e = blockIdx.x * 256 + threadIdx.x;
    if (e < E) {
        int d = dst[e];
        if (d >= lo && d < hi) {
            int p = row_ptr[d] + atomicAdd(&cursor[d], 1);
            src_sorted[p] = src[e];
        }
    }
}

// ---------------- layer-1 matmul: Apart[q][N][16] = x[:, kq] @ W0[kq, :] ----------------
// K-split x4 for wave count (24 waves/CU), class-pure waves for alignment:
// wave wv handles rows n = n0 + wv + 4*lane -> all lanes share (n*IN mod 4), and
// K-chunk starts are multiples of 4, so the float4-alignment head is wave-uniform
// (readfirstlane -> SGPR), the k loop is uniform, and W0[k*16+j] indices are
// wave-uniform -> s_load (constant cache). Inner loop: 1 global_load_dwordx4 +
// 64 v_fma with SGPR operands per 4 k. 16 acc chains of ILP, no LDS, no barriers.

__global__ __launch_bounds__(256) void mm0_kernel(const float* __restrict__ x,
                                                  const float* __restrict__ W0,
                                                  float* __restrict__ Apart, int N, int in_ch) {
    int tid = threadIdx.x;
    int wv = tid >> 6, lane = tid & 63;
    int q = blockIdx.y;
    long n = (long)blockIdx.x * 256 + wv + 4 * (long)lane;
    if (n >= N) return;

    int kc = ((in_ch + 3) >> 2) & ~3;            // 124 (multiple of 4)
    int kbeg = q * kc;
    int kend = (q == 3) ? in_ch : kbeg + kc;
    const float* xr = x + n * (long)in_ch;

    float acc[16];
    #pragma unroll
    for (int j = 0; j < 16; ++j) acc[j] = 0.f;

    int head = (int)((4 - ((n * (long)in_ch + kbeg) & 3)) & 3);
    head = __builtin_amdgcn_readfirstlane(head);   // wave-uniform by construction

    int k = kbeg;
    int hend = kbeg + head; if (hend > kend) hend = kend;
    for (; k < hend; ++k) {
        float xv = xr[k];
        #pragma unroll
        for (int j = 0; j < 16; ++j) acc[j] = fmaf(xv, W0[k * 16 + j], acc[j]);
    }
    int kend4 = k + (((kend - k) >> 2) << 2);
    for (; k < kend4; k += 4) {
        float4 xv = *(const float4*)(xr + k);   // 16B-aligned by construction
        float xa[4] = {xv.x, xv.y, xv.z, xv.w};
        #pragma unroll
        for (int u = 0; u < 4; ++u) {
            #pragma unroll
            for (int j = 0; j < 16; ++j)
                acc[j] = fmaf(xa[u], W0[(k + u) * 16 + j], acc[j]);
        }
    }
    for (; k < kend; ++k) {
        float xv = xr[k];
        #pragma unroll
        for (int j = 0; j < 16; ++j) acc[j] = fmaf(xv, W0[k * 16 + j], acc[j]);
    }

    float4* out = (float4*)(Apart + (size_t)q * N * 16 + n * 16);
    out[0] = make_float4(acc[0],  acc[1],  acc[2],  acc[3]);
    out[1] = make_float4(acc[4],  acc[5],  acc[6],  acc[7]);
    out[2] = make_float4(acc[8],  acc[9],  acc[10], acc[11]);
    out[3] = make_float4(acc[12], acc[13], acc[14], acc[15]);
}

__global__ __launch_bounds__(256) void reduce4_kernel(const float* __restrict__ Ap,
                                                      float* __restrict__ A, int nq, int stride4) {
    int i = blockIdx.x * 256 + threadIdx.x;
    if (i >= nq) return;
    const float4* p = (const float4*)Ap;
    float4 a = p[i];
    float4 b = p[i + stride4];
    float4 c = p[i + 2 * stride4];
    float4 d = p[i + 3 * stride4];
    ((float4*)A)[i] = make_float4(a.x + b.x + c.x + d.x, a.y + b.y + c.y + d.y,
                                  a.z + b.z + c.z + d.z, a.w + b.w + c.w + d.w);
}

// ---------------- small matmul: Aout[N][16] = Hin[N][16] @ W[16][16] ----------------

__global__ __launch_bounds__(256) void mm16_kernel(const float* __restrict__ Hin,
                                                   const float* __restrict__ W,
                                                   float* __restrict__ Aout, int N) {
    __shared__ float ws[256];
    ws[threadIdx.x] = W[threadIdx.x];
    __syncthreads();
    int t = blockIdx.x * 256 + threadIdx.x;
    int n = t >> 4, j = t & 15;
    if (n >= N) return;
    const float* hrow = Hin + n * 16;
    float acc = 0.f;
    #pragma unroll
    for (int k = 0; k < 16; ++k) acc = fmaf(hrow[k], ws[k * 16 + j], acc);
    Aout[n * 16 + j] = acc;
}

// ---------------- pull propagation ----------------

__global__ __launch_bounds__(256) void prop_kernel(const float* __restrict__ A,
                                                   const float* __restrict__ dis,
                                                   const int* __restrict__ row_ptr,
                                                   const int* __restrict__ src_sorted,
                                                   const float* __restrict__ bias,
                                                   float* __restrict__ B, int N) {
    int wid = (blockIdx.x << 2) + (threadIdx.x >> 6);
    if (wid >= N) return;
    int lane = threadIdx.x & 63;
    int j = lane & 15, q = lane >> 4;
    int start = row_ptr[wid], end = row_ptr[wid + 1];
    float acc = 0.f;
    for (int e = start + q; e < end; e += 4) {
        int s = src_sorted[e];
        acc = fmaf(A[s * 16 + j], dis[s], acc);
    }
    acc += __shfl_xor(acc, 16);
    acc += __shfl_xor(acc, 32);
    if (q == 0) {
        float dn = dis[wid];
        float v = dn * acc + dn * dn * A[wid * 16 + j] + bias[j];
        B[wid * 16 + j] = fmaxf(v, 0.f);
    }
}

// ---------------- edge head ----------------

__global__ __launch_bounds__(256) void head_kernel(const float* __restrict__ H,
                                                   const int* __restrict__ src,
                                                   const int* __restrict__ dst,
                                                   const float* __restrict__ Wf0,
                                                   const float* __restrict__ bf0,
                                                   const float* __restrict__ Wf1,
                                                   const float* __restrict__ bf1,
                                                   float* __restrict__ out, int E) {
    int e = blockIdx.x * 256 + threadIdx.x;
    if (e >= E) return;
    int s = src[e], d = dst[e];
    const float4* hs = (const float4*)(H + s * 16);
    const float4* hd = (const float4*)(H + d * 16);
    float ef[32];
    #pragma unroll
    for (int i = 0; i < 4; ++i) {
        float4 v = hs[i];
        ef[i * 4 + 0] = v.x; ef[i * 4 + 1] = v.y; ef[i * 4 + 2] = v.z; ef[i * 4 + 3] = v.w;
    }
    #pragma unroll
    for (int i = 0; i < 4; ++i) {
        float4 v = hd[i];
        ef[16 + i * 4 + 0] = v.x; ef[16 + i * 4 + 1] = v.y; ef[16 + i * 4 + 2] = v.z; ef[16 + i * 4 + 3] = v.w;
    }
    float hid[16];
    #pragma unroll
    for (int jj = 0; jj < 16; ++jj) hid[jj] = bf0[jj];
    #pragma unroll
    for (int k = 0; k < 32; ++k) {
        float ek = ef[k];
        #pragma unroll
        for (int jj = 0; jj < 16; ++jj) hid[jj] = fmaf(ek, Wf0[k * 16 + jj], hid[jj]);
    }
    float o = bf1[0];
    #pragma unroll
    for (int jj = 0; jj < 16; ++jj) o = fmaf(fmaxf(hid[jj], 0.f), Wf1[jj], o);
    out[e] = o;
}

// ---------------- launch ----------------

extern "C" void kernel_launch(void* const* d_in, const int* in_sizes, int n_in,
                              void* d_out, int out_size, void* d_ws, size_t ws_size,
                              hipStream_t stream) {
    const float* x   = (const float*)d_in[0];
    const int*   ei  = (const int*)d_in[1];
    const float* W0  = (const float*)d_in[2];
    const float* b0  = (const float*)d_in[3];
    const float* W1  = (const float*)d_in[4];
    const float* b1  = (const float*)d_in[5];
    const float* W2  = (const float*)d_in[6];
    const float* b2  = (const float*)d_in[7];
    const float* Wf0 = (const float*)d_in[8];
    const float* bf0 = (const float*)d_in[9];
    const float* Wf1 = (const float*)d_in[10];
    const float* bf1 = (const float*)d_in[11];

    const int H  = 16;
    const int IN = in_sizes[2] / H;        // 495
    const int N  = in_sizes[0] / IN;       // 100000
    const int E  = in_sizes[1] / 2;        // 3200000
    const int* src = ei;
    const int* dst = ei + E;

    char* ws = (char*)d_ws;
    size_t off = 0;
    auto alloc = [&](size_t bytes) {
        void* p = ws + off;
        off = (off + bytes + 255) & ~size_t(255);
        return p;
    };
    int*   hist       = (int*)alloc((size_t)N * 4);
    int*   cursor     = (int*)alloc((size_t)N * 4);
    int*   row_ptr    = (int*)alloc((size_t)(N + 1) * 4);
    int*   partials   = (int*)alloc((size_t)((N + 255) / 256) * 4);
    float* dis        = (float*)alloc((size_t)N * 4);
    int*   src_sorted = (int*)alloc((size_t)E * 4);
    float* A          = (float*)alloc((size_t)N * 16 * 4);
    float* B          = (float*)alloc((size_t)N * 16 * 4);
    float* Apart      = (float*)alloc((size_t)4 * N * 16 * 4);

    int gE = (E + 255) / 256;
    int gN = (N + 255) / 256;

    hipMemsetAsync(hist, 0, (size_t)N * 4, stream);
    hipMemsetAsync(cursor, 0, (size_t)N * 4, stream);

    hist_kernel<<<gE, 256, 0, stream>>>(dst, hist, E);
    dis_kernel<<<gN, 256, 0, stream>>>(hist, dis, N);
    scan_part_kernel<<<gN, 256, 0, stream>>>(hist, partials, N);
    scan_top_kernel<<<1, 1024, 0, stream>>>(partials, gN);
    scan_final_kernel<<<gN, 256, 0, stream>>>(hist, partials, row_ptr, N);

    // multi-pass scatter: 8 dst-range passes, each with an L2-resident write window
    const int NPASS = 8;
    int npp = (N + NPASS - 1) / NPASS;
    for (int p = 0; p < NPASS; ++p) {
        int lo = p * npp;
        int hi = (lo + npp < N) ? lo + npp : N;
        fill_kernel<<<gE, 256, 0, stream>>>(src, dst, row_ptr, cursor, src_sorted, E, lo, hi);
    }

    dim3 g0((N + 255) / 256, 4);
    mm0_kernel<<<g0, 256, 0, stream>>>(x, W0, Apart, N, IN);
    int nq = N * 16 / 4;  // float4 count per slice
    reduce4_kernel<<<(nq + 255) / 256, 256, 0, stream>>>(Apart, A, nq, nq);

    prop_kernel<<<(N + 3) / 4, 256, 0, stream>>>(A, dis, row_ptr, src_sorted, b0, B, N);
    mm16_kernel<<<(N * 16 + 255) / 256, 256, 0, stream>>>(B, W1, A, N);
    prop_kernel<<<(N + 3) / 4, 256, 0, stream>>>(A, dis, row_ptr, src_sorted, b1, B, N);
    mm16_kernel<<<(N * 16 + 255) / 256, 256, 0, stream>>>(B, W2, A, N);
    prop_kernel<<<(N + 3) / 4, 256, 0, stream>>>(A, dis, row_ptr, src_sorted, b2, B, N);
    head_kernel<<<gE, 256, 0, stream>>>(B, src, dst, Wf0, bf0, Wf1, bf1, (float*)d_out, E);
}

// Round 7
// 745.776 us; speedup vs baseline: 1.2379x; 1.2379x over previous
//
#include <hip/hip_runtime.h>

// ---------------- degree / norm ----------------

__global__ __launch_bounds__(256) void hist_kernel(const int* __restrict__ dst,
                                                   int* __restrict__ hist, int E) {
    int e = blockIdx.x * 256 + threadIdx.x;
    if (e < E) atomicAdd(&hist[dst[e]], 1);
}

__global__ __launch_bounds__(256) void dis_kernel(const int* __restrict__ hist,
                                                  float* __restrict__ dis, int N) {
    int n = blockIdx.x * 256 + threadIdx.x;
    if (n < N) dis[n] = 1.0f / sqrtf((float)(hist[n] + 1));  // +1 self-loop; deg>=1
}

// ---------------- CSR build: reduce -> top scan -> final scan -> fill ----------------

__global__ __launch_bounds__(256) void scan_part_kernel(const int* __restrict__ hist,
                                                        int* __restrict__ partials, int n) {
    __shared__ int sdata[256];
    int i = blockIdx.x * 256 + threadIdx.x;
    int t = threadIdx.x;
    sdata[t] = (i < n) ? hist[i] : 0;
    __syncthreads();
    for (int off = 128; off > 0; off >>= 1) {
        if (t < off) sdata[t] += sdata[t + off];
        __syncthreads();
    }
    if (t == 0) partials[blockIdx.x] = sdata[0];
}

__global__ __launch_bounds__(1024) void scan_top_kernel(int* __restrict__ partials, int nb) {
    __shared__ int sdata[1024];
    int t = threadIdx.x;
    int v = (t < nb) ? partials[t] : 0;
    sdata[t] = v;
    __syncthreads();
    for (int off = 1; off < 1024; off <<= 1) {
        int x = (t >= off) ? sdata[t - off] : 0;
        __syncthreads();
        sdata[t] += x;
        __syncthreads();
    }
    if (t < nb) partials[t] = sdata[t] - v;  // exclusive
}

__global__ __launch_bounds__(256) void scan_final_kernel(const int* __restrict__ hist,
                                                         const int* __restrict__ partials,
                                                         int* __restrict__ row_ptr, int n) {
    __shared__ int sdata[256];
    int i = blockIdx.x * 256 + threadIdx.x;
    int t = threadIdx.x;
    int v = (i < n) ? hist[i] : 0;
    sdata[t] = v;
    __syncthreads();
    for (int off = 1; off < 256; off <<= 1) {
        int x = (t >= off) ? sdata[t - off] : 0;
        __syncthreads();
        sdata[t] += x;
        __syncthreads();
    }
    int base = partials[blockIdx.x];
    if (i < n) row_ptr[i] = base + sdata[t] - v;  // exclusive
    if (i == n - 1) row_ptr[n] = base + sdata[t]; // total = E
}

// dst-range pass: only edges with dst in [lo,hi) are scattered this pass, so the
// active write window of src_sorted is ~1.6 MB -> L2-resident -> dense writeback.
__global__ __launch_bounds__(256) void fill_kernel(const int* __restrict__ src,
                                                   const int* __restrict__ dst,
                                                   const int* __restrict__ row_ptr,
                                                   int* __restrict__ cursor,
                                                   int* __restrict__ src_sorted, int E,
                                                   int lo, int hi) {
    int e = blockIdx.x * 256 + threadIdx.x;
    if (e < E) {
        int d = dst[e];
        if (d >= lo && d < hi) {
            int p = row_ptr[d] + atomicAdd(&cursor[d], 1);
            src_sorted[p] = src[e];
        }
    }
}

// ---------------- layer-1 matmul: Apart[q][N][16] = x[:, kq] @ W0[kq, :] ----------------
// 128-row tile, K-split x4 (blockIdx.y), 256 threads, double-buffered LDS with
// software pipelining: issue next step's global loads (to regs) BEFORE computing
// the current step, so HBM latency hides under the 32-k FMA phase. One barrier
// per step suffices with the double buffer (write(t+1) ordered after
// compute(t-1) through barrier(t)). Staging is row-chunk coalesced (2x128B per
// wave instr); LDS pad 33 keeps reads conflict-free; compute = 2 rows x 4 cols.

#define MM0_TM 128
#define MM0_KS 32

__global__ __launch_bounds__(256) void mm0_kernel(const float* __restrict__ x,
                                                  const float* __restrict__ W0,
                                                  float* __restrict__ Apart, int N, int in_ch) {
    __shared__ float xs[2][MM0_TM][33];
    __shared__ float wsh[2][MM0_KS][16];
    int tid = threadIdx.x;
    int q = blockIdx.y;
    long n0 = (long)blockIdx.x * MM0_TM;

    int kc = ((in_ch + 3) >> 2) & ~3;            // 124 (multiple of 4)
    int kbeg = q * kc;
    int kend = (q == 3) ? in_ch : kbeg + kc;
    int nsteps = (kend - kbeg + MM0_KS - 1) / MM0_KS;

    int tn = tid >> 2, tj = tid & 3;             // 64 row-pairs x 4 col-groups
    float acc[2][4] = {};
    float xreg[16];
    float wreg[2];

    // prologue: loads for step 0
    {
        int k0 = kbeg;
        #pragma unroll
        for (int it = 0; it < 16; ++it) {
            int idx = (it << 8) + tid;
            int nn = idx >> 5, kk = idx & 31;
            long node = n0 + nn;
            int k = k0 + kk;
            xreg[it] = (node < N && k < kend) ? x[node * (long)in_ch + k] : 0.f;
        }
        #pragma unroll
        for (int it = 0; it < 2; ++it) {
            int idx = (it << 8) + tid;
            int kk = idx >> 4, j = idx & 15;
            int k = k0 + kk;
            wreg[it] = (k < kend) ? W0[k * 16 + j] : 0.f;
        }
    }

    int cur = 0;
    for (int step = 0; step < nsteps; ++step) {
        // write staged regs -> LDS[cur]
        #pragma unroll
        for (int it = 0; it < 16; ++it) {
            int idx = (it << 8) + tid;
            xs[cur][idx >> 5][idx & 31] = xreg[it];
        }
        #pragma unroll
        for (int it = 0; it < 2; ++it) {
            int idx = (it << 8) + tid;
            wsh[cur][idx >> 4][idx & 15] = wreg[it];
        }
        __syncthreads();

        // issue next step's loads (overlap with compute below)
        if (step + 1 < nsteps) {
            int k0 = kbeg + (step + 1) * MM0_KS;
            #pragma unroll
            for (int it = 0; it < 16; ++it) {
                int idx = (it << 8) + tid;
                int nn = idx >> 5, kk = idx & 31;
                long node = n0 + nn;
                int k = k0 + kk;
                xreg[it] = (node < N && k < kend) ? x[node * (long)in_ch + k] : 0.f;
            }
            #pragma unroll
            for (int it = 0; it < 2; ++it) {
                int idx = (it << 8) + tid;
                int kk = idx >> 4, j = idx & 15;
                int k = k0 + kk;
                wreg[it] = (k < kend) ? W0[k * 16 + j] : 0.f;
            }
        }

        // compute 32 k from LDS[cur]
        #pragma unroll
        for (int kk = 0; kk < MM0_KS; ++kk) {
            float4 wr = *(const float4*)&wsh[cur][kk][tj * 4];
            float x0 = xs[cur][tn * 2 + 0][kk];
            float x1 = xs[cur][tn * 2 + 1][kk];
            acc[0][0] = fmaf(x0, wr.x, acc[0][0]);
            acc[0][1] = fmaf(x0, wr.y, acc[0][1]);
            acc[0][2] = fmaf(x0, wr.z, acc[0][2]);
            acc[0][3] = fmaf(x0, wr.w, acc[0][3]);
            acc[1][0] = fmaf(x1, wr.x, acc[1][0]);
            acc[1][1] = fmaf(x1, wr.y, acc[1][1]);
            acc[1][2] = fmaf(x1, wr.z, acc[1][2]);
            acc[1][3] = fmaf(x1, wr.w, acc[1][3]);
        }
        cur ^= 1;
    }

    float* outb = Apart + (size_t)q * N * 16;
    #pragma unroll
    for (int i = 0; i < 2; ++i) {
        long node = n0 + tn * 2 + i;
        if (node < N) {
            *(float4*)(outb + node * 16 + tj * 4) =
                make_float4(acc[i][0], acc[i][1], acc[i][2], acc[i][3]);
        }
    }
}

__global__ __launch_bounds__(256) void reduce4_kernel(const float* __restrict__ Ap,
                                                      float* __restrict__ A, int nq, int stride4) {
    int i = blockIdx.x * 256 + threadIdx.x;
    if (i >= nq) return;
    const float4* p = (const float4*)Ap;
    float4 a = p[i];
    float4 b = p[i + stride4];
    float4 c = p[i + 2 * stride4];
    float4 d = p[i + 3 * stride4];
    ((float4*)A)[i] = make_float4(a.x + b.x + c.x + d.x, a.y + b.y + c.y + d.y,
                                  a.z + b.z + c.z + d.z, a.w + b.w + c.w + d.w);
}

// ---------------- small matmul: Aout[N][16] = Hin[N][16] @ W[16][16] ----------------

__global__ __launch_bounds__(256) void mm16_kernel(const float* __restrict__ Hin,
                                                   const float* __restrict__ W,
                                                   float* __restrict__ Aout, int N) {
    __shared__ float ws[256];
    ws[threadIdx.x] = W[threadIdx.x];
    __syncthreads();
    int t = blockIdx.x * 256 + threadIdx.x;
    int n = t >> 4, j = t & 15;
    if (n >= N) return;
    const float* hrow = Hin + n * 16;
    float acc = 0.f;
    #pragma unroll
    for (int k = 0; k < 16; ++k) acc = fmaf(hrow[k], ws[k * 16 + j], acc);
    Aout[n * 16 + j] = acc;
}

// ---------------- pull propagation ----------------

__global__ __launch_bounds__(256) void prop_kernel(const float* __restrict__ A,
                                                   const float* __restrict__ dis,
                                                   const int* __restrict__ row_ptr,
                                                   const int* __restrict__ src_sorted,
                                                   const float* __restrict__ bias,
                                                   float* __restrict__ B, int N) {
    int wid = (blockIdx.x << 2) + (threadIdx.x >> 6);
    if (wid >= N) return;
    int lane = threadIdx.x & 63;
    int j = lane & 15, q = lane >> 4;
    int start = row_ptr[wid], end = row_ptr[wid + 1];
    float acc = 0.f;
    for (int e = start + q; e < end; e += 4) {
        int s = src_sorted[e];
        acc = fmaf(A[s * 16 + j], dis[s], acc);
    }
    acc += __shfl_xor(acc, 16);
    acc += __shfl_xor(acc, 32);
    if (q == 0) {
        float dn = dis[wid];
        float v = dn * acc + dn * dn * A[wid * 16 + j] + bias[j];
        B[wid * 16 + j] = fmaxf(v, 0.f);
    }
}

// ---------------- edge head ----------------

__global__ __launch_bounds__(256) void head_kernel(const float* __restrict__ H,
                                                   const int* __restrict__ src,
                                                   const int* __restrict__ dst,
                                                   const float* __restrict__ Wf0,
                                                   const float* __restrict__ bf0,
                                                   const float* __restrict__ Wf1,
                                                   const float* __restrict__ bf1,
                                                   float* __restrict__ out, int E) {
    int e = blockIdx.x * 256 + threadIdx.x;
    if (e >= E) return;
    int s = src[e], d = dst[e];
    const float4* hs = (const float4*)(H + s * 16);
    const float4* hd = (const float4*)(H + d * 16);
    float ef[32];
    #pragma unroll
    for (int i = 0; i < 4; ++i) {
        float4 v = hs[i];
        ef[i * 4 + 0] = v.x; ef[i * 4 + 1] = v.y; ef[i * 4 + 2] = v.z; ef[i * 4 + 3] = v.w;
    }
    #pragma unroll
    for (int i = 0; i < 4; ++i) {
        float4 v = hd[i];
        ef[16 + i * 4 + 0] = v.x; ef[16 + i * 4 + 1] = v.y; ef[16 + i * 4 + 2] = v.z; ef[16 + i * 4 + 3] = v.w;
    }
    float hid[16];
    #pragma unroll
    for (int jj = 0; jj < 16; ++jj) hid[jj] = bf0[jj];
    #pragma unroll
    for (int k = 0; k < 32; ++k) {
        float ek = ef[k];
        #pragma unroll
        for (int jj = 0; jj < 16; ++jj) hid[jj] = fmaf(ek, Wf0[k * 16 + jj], hid[jj]);
    }
    float o = bf1[0];
    #pragma unroll
    for (int jj = 0; jj < 16; ++jj) o = fmaf(fmaxf(hid[jj], 0.f), Wf1[jj], o);
    out[e] = o;
}

// ---------------- launch ----------------

extern "C" void kernel_launch(void* const* d_in, const int* in_sizes, int n_in,
                              void* d_out, int out_size, void* d_ws, size_t ws_size,
                              hipStream_t stream) {
    const float* x   = (const float*)d_in[0];
    const int*   ei  = (const int*)d_in[1];
    const float* W0  = (const float*)d_in[2];
    const float* b0  = (const float*)d_in[3];
    const float* W1  = (const float*)d_in[4];
    const float* b1  = (const float*)d_in[5];
    const float* W2  = (const float*)d_in[6];
    const float* b2  = (const float*)d_in[7];
    const float* Wf0 = (const float*)d_in[8];
    const float* bf0 = (const float*)d_in[9];
    const float* Wf1 = (const float*)d_in[10];
    const float* bf1 = (const float*)d_in[11];

    const int H  = 16;
    const int IN = in_sizes[2] / H;        // 495
    const int N  = in_sizes[0] / IN;       // 100000
    const int E  = in_sizes[1] / 2;        // 3200000
    const int* src = ei;
    const int* dst = ei + E;

    char* ws = (char*)d_ws;
    size_t off = 0;
    auto alloc = [&](size_t bytes) {
        void* p = ws + off;
        off = (off + bytes + 255) & ~size_t(255);
        return p;
    };
    int*   hist       = (int*)alloc((size_t)N * 4);
    int*   cursor     = (int*)alloc((size_t)N * 4);
    int*   row_ptr    = (int*)alloc((size_t)(N + 1) * 4);
    int*   partials   = (int*)alloc((size_t)((N + 255) / 256) * 4);
    float* dis        = (float*)alloc((size_t)N * 4);
    int*   src_sorted = (int*)alloc((size_t)E * 4);
    float* A          = (float*)alloc((size_t)N * 16 * 4);
    float* B          = (float*)alloc((size_t)N * 16 * 4);
    float* Apart      = (float*)alloc((size_t)4 * N * 16 * 4);

    int gE = (E + 255) / 256;
    int gN = (N + 255) / 256;

    hipMemsetAsync(hist, 0, (size_t)N * 4, stream);
    hipMemsetAsync(cursor, 0, (size_t)N * 4, stream);

    hist_kernel<<<gE, 256, 0, stream>>>(dst, hist, E);
    dis_kernel<<<gN, 256, 0, stream>>>(hist, dis, N);
    scan_part_kernel<<<gN, 256, 0, stream>>>(hist, partials, N);
    scan_top_kernel<<<1, 1024, 0, stream>>>(partials, gN);
    scan_final_kernel<<<gN, 256, 0, stream>>>(hist, partials, row_ptr, N);

    // multi-pass scatter: 8 dst-range passes, each with an L2-resident write window
    const int NPASS = 8;
    int npp = (N + NPASS - 1) / NPASS;
    for (int p = 0; p < NPASS; ++p) {
        int lo = p * npp;
        int hi = (lo + npp < N) ? lo + npp : N;
        fill_kernel<<<gE, 256, 0, stream>>>(src, dst, row_ptr, cursor, src_sorted, E, lo, hi);
    }

    dim3 g0((N + MM0_TM - 1) / MM0_TM, 4);
    mm0_kernel<<<g0, 256, 0, stream>>>(x, W0, Apart, N, IN);
    int nq = N * 16 / 4;  // float4 count per slice
    reduce4_kernel<<<(nq + 255) / 256, 256, 0, stream>>>(Apart, A, nq, nq);

    prop_kernel<<<(N + 3) / 4, 256, 0, stream>>>(A, dis, row_ptr, src_sorted, b0, B, N);
    mm16_kernel<<<(N * 16 + 255) / 256, 256, 0, stream>>>(B, W1, A, N);
    prop_kernel<<<(N + 3) / 4, 256, 0, stream>>>(A, dis, row_ptr, src_sorted, b1, B, N);
    mm16_kernel<<<(N * 16 + 255) / 256, 256, 0, stream>>>(B, W2, A, N);
    prop_kernel<<<(N + 3) / 4, 256, 0, stream>>>(A, dis, row_ptr, src_sorted, b2, B, N);
    head_kernel<<<gE, 256, 0, stream>>>(B, src, dst, Wf0, bf0, Wf1, bf1, (float*)d_out, E);
}